// Round 3
// baseline (8912.241 us; speedup 1.0000x reference)
//
#include <hip/hip_runtime.h>

// BiLSTM-CRF on MI355X — round 3: fix the latency-bound lstm_scan.
//   * 512-thread blocks (8 waves/CU), k-split 2-way, LDS partial reduce
//   * explicit double-buffered register load batches (8x dwordx4 in flight)
//   * 128 KB of bf16 weights resident in LDS (kk 0..31), 384 KB/step streamed
//
// ws layout: X4 (67108864 B) | WTB (1048576 B) | FT (786432 B) | H (fp32 33554432
// or bf16 16777216, chosen by ws_size).
// Output (float32): d_out[0:16384] = paths (floats, -1 past length), [16384:16448] = best_score.

#define NB 64
#define NT 256
#define NKTAG 12
#define START_TAG 10
#define KK_LDS 32   // kk-pairs resident in LDS (of 128 total) -> 128 KiB

typedef unsigned short u16;
typedef __attribute__((ext_vector_type(8))) unsigned short ushort8v;

__device__ __forceinline__ float b2f(u16 u) {
  union { unsigned int i; float f; } v; v.i = ((unsigned int)u) << 16; return v.f;
}
__device__ __forceinline__ u16 f2b(float f) {
  union { float f; unsigned int i; } v; v.f = f;
  unsigned int r = v.i + 0x7FFFu + ((v.i >> 16) & 1u);
  return (u16)(r >> 16);
}
// packed-bf16 dword -> two floats: low half is bits<<16, high half is bits&0xffff0000
__device__ __forceinline__ float bfl(unsigned int d) {
  union { unsigned int i; float f; } v; v.i = d << 16; return v.f;
}
__device__ __forceinline__ float bfh(unsigned int d) {
  union { unsigned int i; float f; } v; v.i = d & 0xffff0000u; return v.f;
}
__device__ __forceinline__ float fsig(float x) { return 1.0f / (1.0f + __expf(-x)); }
__device__ __forceinline__ float ftanh(float x) { return 2.0f / (1.0f + __expf(-2.0f * x)) - 1.0f; }

// ---------------------------------------------------------------- pack_whh
// WTB[d][kk][j] = bf16x8 {W_i[j][2kk],W_f,W_g,W_o, W_i[j][2kk+1],W_f,W_g,W_o}
__global__ __launch_bounds__(256) void pack_whh(const float* __restrict__ Whf,
                                                const float* __restrict__ Whb,
                                                ushort8v* __restrict__ WT) {
  int gid = blockIdx.x * 256 + threadIdx.x;      // 2*128*256 = 65536
  int d = gid >> 15;
  int rem = gid & 32767;
  int kk = rem >> 8, j = rem & 255;
  const float* W = d ? Whb : Whf;
  int k0 = kk * 2;
  ushort8v o;
  o[0] = f2b(W[(size_t)j * 256 + k0]);
  o[1] = f2b(W[(size_t)(j + 256) * 256 + k0]);
  o[2] = f2b(W[(size_t)(j + 512) * 256 + k0]);
  o[3] = f2b(W[(size_t)(j + 768) * 256 + k0]);
  o[4] = f2b(W[(size_t)j * 256 + k0 + 1]);
  o[5] = f2b(W[(size_t)(j + 256) * 256 + k0 + 1]);
  o[6] = f2b(W[(size_t)(j + 512) * 256 + k0 + 1]);
  o[7] = f2b(W[(size_t)(j + 768) * 256 + k0 + 1]);
  WT[gid] = o;
}

// ---------------------------------------------------------------- gemm_x
// C[i][n] = emb[sent[i]] @ W_all[n]^T + bias[n];  i=(b,t), n=(d,gate,j). fp32.
__global__ __launch_bounds__(256) void gemm_x(const int* __restrict__ sent,
                                              const float* __restrict__ emb,
                                              const float* __restrict__ Wf,
                                              const float* __restrict__ Wb,
                                              const float* __restrict__ bihf,
                                              const float* __restrict__ bhhf,
                                              const float* __restrict__ bihb,
                                              const float* __restrict__ bhhb,
                                              u16* __restrict__ X4) {
  __shared__ float As[16][128];
  __shared__ float Bs[16][64];
  __shared__ int tok[128];
  int tid = threadIdx.x;
  int in = blockIdx.x;   // 0..31
  int im = blockIdx.y;   // 0..127
  if (tid < 128) tok[tid] = sent[im * 128 + tid];
  __syncthreads();
  float acc[8][4];
#pragma unroll
  for (int m = 0; m < 8; ++m)
#pragma unroll
    for (int n = 0; n < 4; ++n) acc[m][n] = 0.f;
  int ty = tid >> 4, tx = tid & 15;
  for (int kt = 0; kt < 16; ++kt) {
    int k0 = kt * 16;
#pragma unroll
    for (int l = 0; l < 2; ++l) {
      int idx = l * 256 + tid;
      int row = idx >> 2, kq = idx & 3;
      const float* ap = emb + (size_t)tok[row] * 256 + k0 + kq * 4;
      float4 av = *(const float4*)ap;
      As[kq * 4 + 0][row] = av.x; As[kq * 4 + 1][row] = av.y;
      As[kq * 4 + 2][row] = av.z; As[kq * 4 + 3][row] = av.w;
    }
    {
      int nrow = tid >> 2, kq = tid & 3;
      int ng = in * 64 + nrow;
      const float* wrow = (ng < 1024) ? (Wf + (size_t)ng * 256) : (Wb + (size_t)(ng - 1024) * 256);
      float4 bv = *(const float4*)(wrow + k0 + kq * 4);
      Bs[kq * 4 + 0][nrow] = bv.x; Bs[kq * 4 + 1][nrow] = bv.y;
      Bs[kq * 4 + 2][nrow] = bv.z; Bs[kq * 4 + 3][nrow] = bv.w;
    }
    __syncthreads();
#pragma unroll
    for (int k = 0; k < 16; ++k) {
      float4 a0 = *(const float4*)&As[k][ty * 8];
      float4 a1 = *(const float4*)&As[k][ty * 8 + 4];
      float4 bb = *(const float4*)&Bs[k][tx * 4];
      float am[8] = {a0.x, a0.y, a0.z, a0.w, a1.x, a1.y, a1.z, a1.w};
      float bn[4] = {bb.x, bb.y, bb.z, bb.w};
#pragma unroll
      for (int m = 0; m < 8; ++m)
#pragma unroll
        for (int n = 0; n < 4; ++n) acc[m][n] += am[m] * bn[n];
    }
    __syncthreads();
  }
#pragma unroll
  for (int n = 0; n < 4; ++n) {
    int ng = in * 64 + tx * 4 + n;
    int d = ng >> 10, r = ng & 1023;
    int g = r >> 8, j = r & 255;
    float bias = d ? (bihb[r] + bhhb[r]) : (bihf[r] + bhhf[r]);
#pragma unroll
    for (int m = 0; m < 8; ++m) {
      int i = im * 128 + ty * 8 + m;
      int bb_ = i >> 8, tt = i & 255;
      size_t o = ((((size_t)d * NT + tt) * NB + bb_) * 256 + j) * 4 + g;
      X4[o] = f2b(acc[m][n] + bias);
    }
  }
}

// ---------------------------------------------------------------- lstm_scan
// One block per (dir d, batch b), 512 threads = (jj 0..255, half 0..1).
// half handles kk in [half*16, half*16+16) from LDS and [32+half*48, +48) from L2.
// Partials combined via LDS; half 0 owns c and the gate nonlinearity.
#define ACC8(wv, h0v, h1v)                                        \
  do {                                                            \
    ai += bfl(wv.x) * h0v; af += bfh(wv.x) * h0v;                 \
    ag += bfl(wv.y) * h0v; ao += bfh(wv.y) * h0v;                 \
    ai += bfl(wv.z) * h1v; af += bfh(wv.z) * h1v;                 \
    ag += bfl(wv.w) * h1v; ao += bfh(wv.w) * h1v;                 \
  } while (0)

#define LOADB(buf, kb)                                            \
  _Pragma("unroll") for (int u = 0; u < 8; ++u)                   \
      buf[u] = Ws[(size_t)((kb) + u) * 256 + jj];

#define CONSB(buf, kb)                                            \
  _Pragma("unroll") for (int u = 0; u < 8; ++u) {                 \
    float2 hp = *(const float2*)&h_lds[((kb) + u) * 2];           \
    uint4 wv = buf[u];                                            \
    ACC8(wv, hp.x, hp.y);                                         \
  }

__global__ __launch_bounds__(512, 2) void lstm_scan(const uint4* __restrict__ WT,
                                                    const ushort4* __restrict__ X4,
                                                    const float* __restrict__ h0,
                                                    const float* __restrict__ c0,
                                                    void* __restrict__ H, int h32) {
  int d = blockIdx.x >> 6, b = blockIdx.x & 63;
  int tid = threadIdx.x;
  int jj = tid & 255, half = tid >> 8;
  __shared__ uint4 wlds[KK_LDS * 256];   // 128 KiB: kk 0..31, [kk][j]
  __shared__ float h_lds[256];
  __shared__ float4 plds[256];
  const uint4* Ws = WT + (size_t)d * 32768;  // [kk][jj], 128 x 256 entries
  // preload LDS-resident weight region (first 32 kk rows, flat copy)
  for (int e = tid; e < KK_LDS * 256; e += 512) wlds[e] = Ws[e];
  float c = 0.f;
  if (half == 0) c = c0[((size_t)d * NB + b) * 256 + jj];
  if (tid < 256) h_lds[tid] = h0[((size_t)d * NB + b) * 256 + tid];
  __syncthreads();
  for (int s = 0; s < NT; ++s) {
    int t = d ? (NT - 1 - s) : s;
    float ai, af, ag, ao;
    if (half == 0) {
      ushort4 xg = X4[(((size_t)d * NT + t) * NB + b) * 256 + jj];
      ai = b2f(xg.x); af = b2f(xg.y); ag = b2f(xg.z); ao = b2f(xg.w);
    } else {
      ai = af = ag = ao = 0.f;
    }
    // streamed region: 48 kk's, double-buffered 8-deep dwordx4 batches
    const int kk0 = KK_LDS + half * 48;
    uint4 bufA[8], bufB[8];
    LOADB(bufA, kk0);
    LOADB(bufB, kk0 + 8);
    // LDS-resident region: 16 kk's (overlaps with the in-flight global loads)
    {
      int klb = half * 16;
#pragma unroll
      for (int u = 0; u < 16; ++u) {
        int kk = klb + u;
        uint4 wv = wlds[(kk << 8) | jj];
        float2 hp = *(const float2*)&h_lds[kk * 2];
        ACC8(wv, hp.x, hp.y);
      }
    }
    CONSB(bufA, kk0);
    LOADB(bufA, kk0 + 16);
    CONSB(bufB, kk0 + 8);
    LOADB(bufB, kk0 + 24);
    CONSB(bufA, kk0 + 16);
    LOADB(bufA, kk0 + 32);
    CONSB(bufB, kk0 + 24);
    LOADB(bufB, kk0 + 40);
    CONSB(bufA, kk0 + 32);
    CONSB(bufB, kk0 + 40);
    if (half == 1) plds[jj] = make_float4(ai, af, ag, ao);
    __syncthreads();    // partials visible; all h_lds reads for this step done
    if (half == 0) {
      float4 p = plds[jj];
      ai += p.x; af += p.y; ag += p.z; ao += p.w;
      float ii = fsig(ai), ff = fsig(af), gg = ftanh(ag), oo = fsig(ao);
      c = ff * c + ii * gg;
      float h = oo * ftanh(c);
      h_lds[jj] = h;
      size_t ho = (((size_t)d * NB + b) * NT + t) * 256 + jj;
      if (h32) ((float*)H)[ho] = h; else ((u16*)H)[ho] = f2b(h);
    }
    __syncthreads();    // h_lds updated before next step reads
  }
}

// ---------------------------------------------------------------- feats
// feats[b][t][k] = sum_j hf*Wp[k][j] + hb*Wp[k][256+j] + bp[k]
__global__ __launch_bounds__(384) void feats_kernel(const void* __restrict__ H, int h32,
                                                    const float* __restrict__ Wp,
                                                    const float* __restrict__ bp,
                                                    float* __restrict__ FT) {
  __shared__ float hbuf[32][516];
  int tid = threadIdx.x;
  int i0 = blockIdx.x * 32;
  for (int idx = tid; idx < 32 * 512; idx += 384) {
    int row = idx >> 9, col = idx & 511;
    int i = i0 + row;
    int b = i >> 8, t = i & 255;
    int dd = col >> 8, jj = col & 255;
    size_t ho = (((size_t)dd * NB + b) * NT + t) * 256 + jj;
    hbuf[row][col] = h32 ? ((const float*)H)[ho] : b2f(((const u16*)H)[ho]);
  }
  __syncthreads();
  int row = tid / 12, k = tid - row * 12;  // 384 = 32*12
  const float* wp = Wp + (size_t)k * 512;
  float s = 0.f;
  for (int ccol = 0; ccol < 512; ++ccol) s += hbuf[row][ccol] * wp[ccol];
  int i = i0 + row;
  FT[(size_t)i * NKTAG + k] = s + bp[k];
}

// ---------------------------------------------------------------- viterbi
__global__ __launch_bounds__(64) void viterbi_kernel(const float* __restrict__ FT,
                                                     const float* __restrict__ trans,
                                                     const int* __restrict__ sent,
                                                     float* __restrict__ out) {
  int b = blockIdx.x, tid = threadIdx.x;
  __shared__ float trans_s[12][12];
  __shared__ float s_s[12];
  __shared__ unsigned char bp_s[256][12];
  __shared__ int path_s[256];
  for (int idx = tid; idx < 144; idx += 64) trans_s[idx / 12][idx % 12] = trans[idx];
  int cnt = 0;
#pragma unroll
  for (int q = 0; q < 4; ++q) cnt += (sent[b * NT + q * 64 + tid] > 0) ? 1 : 0;
  for (int off = 32; off; off >>= 1) cnt += __shfl_down(cnt, off);
  int len = __shfl(cnt, 0);
  if (tid < 12) s_s[tid] = (tid == START_TAG) ? 0.f : -10000.f;
  __syncthreads();
  for (int t = 0; t < NT; ++t) {
    float best = 0.f, f = 0.f;
    int barg = 0;
    if (tid < 12) {
      f = FT[((size_t)b * NT + t) * NKTAG + tid];
      best = s_s[0] + trans_s[tid][0];
      barg = 0;
#pragma unroll
      for (int fr = 1; fr < 12; ++fr) {
        float v = s_s[fr] + trans_s[tid][fr];
        if (v > best) { best = v; barg = fr; }  // strict > keeps first (jnp.argmax)
      }
    }
    __syncthreads();
    if (tid < 12) {
      s_s[tid] = best + f;
      bp_s[t][tid] = (unsigned char)barg;
    }
    __syncthreads();
  }
  if (tid == 0) {
    float bs = s_s[0];
    int bt = 0;
    for (int k = 1; k < 12; ++k)
      if (s_s[k] > bs) { bs = s_s[k]; bt = k; }
    out[NB * NT + b] = bs;  // best_score
    int x = bt;
    for (int tt = NT - 1; tt >= 0; --tt) {
      path_s[tt] = x;                  // emit BEFORE stepping back (ref semantics)
      int nxt = bp_s[tt][x];
      if (tt < len) x = nxt;
    }
  }
  __syncthreads();
#pragma unroll
  for (int q = 0; q < 4; ++q) {
    int t = q * 64 + tid;
    out[b * NT + t] = (t < len) ? (float)path_s[t] : -1.0f;
  }
}

// ---------------------------------------------------------------- launch
extern "C" void kernel_launch(void* const* d_in, const int* in_sizes, int n_in,
                              void* d_out, int out_size, void* d_ws, size_t ws_size,
                              hipStream_t stream) {
  (void)in_sizes; (void)n_in; (void)out_size;
  const int*   sent  = (const int*)d_in[0];
  const float* emb   = (const float*)d_in[2];
  const float* Wih_f = (const float*)d_in[3];
  const float* Whh_f = (const float*)d_in[4];
  const float* bih_f = (const float*)d_in[5];
  const float* bhh_f = (const float*)d_in[6];
  const float* Wih_b = (const float*)d_in[7];
  const float* Whh_b = (const float*)d_in[8];
  const float* bih_b = (const float*)d_in[9];
  const float* bhh_b = (const float*)d_in[10];
  const float* Wp    = (const float*)d_in[11];
  const float* bp    = (const float*)d_in[12];
  const float* trans = (const float*)d_in[13];
  const float* h0    = (const float*)d_in[14];
  const float* c0    = (const float*)d_in[15];
  float* out = (float*)d_out;

  char* w = (char*)d_ws;
  u16*   X4  = (u16*)w;                                   // 67108864 B
  ushort8v* WTB = (ushort8v*)(w + 67108864);              //  1048576 B
  float* FT  = (float*)(w + 67108864 + 1048576);          //   786432 B
  void*  H   = (void*)(w + 67108864 + 1048576 + 786432);  // fp32 33554432 or bf16 16777216
  const size_t base = 67108864 + 1048576 + 786432;
  int h32 = (ws_size >= base + (size_t)33554432) ? 1 : 0;

  pack_whh<<<dim3(256), dim3(256), 0, stream>>>(Whh_f, Whh_b, WTB);
  gemm_x<<<dim3(32, 128), dim3(256), 0, stream>>>(sent, emb, Wih_f, Wih_b,
                                                  bih_f, bhh_f, bih_b, bhh_b, X4);
  lstm_scan<<<dim3(128), dim3(512), 0, stream>>>((const uint4*)WTB, (const ushort4*)X4,
                                                 h0, c0, H, h32);
  feats_kernel<<<dim3(512), dim3(384), 0, stream>>>(H, h32, Wp, bp, FT);
  viterbi_kernel<<<dim3(64), dim3(64), 0, stream>>>(FT, trans, sent, out);
}

// Round 4
// 1638.992 us; speedup vs baseline: 5.4376x; 5.4376x over previous
//
#include <hip/hip_runtime.h>

// BiLSTM-CRF on MI355X — round 4: lstm_scan latency fix via TLP, not ILP.
// Round-3 post-mortem: 16-deep manual ILP + blocked dual cursors destroyed L2
// residency (FETCH 37MB -> 8GB). Round 4 returns to the round-2 load shape
// (simple unrolled sweep, single coherent sliding window) with 1024-thread
// blocks and a fine-grained interleaved 4-way k-split (kk = 4u+g).
//
// ws layout: X4 (67108864 B) | WTB (1048576 B) | FT (786432 B) | H (fp32 33554432
// or bf16 16777216, chosen by ws_size).
// Output (float32): d_out[0:16384] = paths (floats, -1 past length), [16384:16448] = best_score.

#define NB 64
#define NT 256
#define NKTAG 12
#define START_TAG 10

typedef unsigned short u16;
typedef __attribute__((ext_vector_type(8))) unsigned short ushort8v;

__device__ __forceinline__ float b2f(u16 u) {
  union { unsigned int i; float f; } v; v.i = ((unsigned int)u) << 16; return v.f;
}
__device__ __forceinline__ u16 f2b(float f) {
  union { float f; unsigned int i; } v; v.f = f;
  unsigned int r = v.i + 0x7FFFu + ((v.i >> 16) & 1u);
  return (u16)(r >> 16);
}
// packed-bf16 dword -> two floats: low half = bits<<16, high half = bits&0xffff0000
__device__ __forceinline__ float bfl(unsigned int d) {
  union { unsigned int i; float f; } v; v.i = d << 16; return v.f;
}
__device__ __forceinline__ float bfh(unsigned int d) {
  union { unsigned int i; float f; } v; v.i = d & 0xffff0000u; return v.f;
}
__device__ __forceinline__ float fsig(float x) { return 1.0f / (1.0f + __expf(-x)); }
__device__ __forceinline__ float ftanh(float x) { return 2.0f / (1.0f + __expf(-2.0f * x)) - 1.0f; }

// ---------------------------------------------------------------- pack_whh
// WTB[d][kk][j] = bf16x8 {W_i[j][2kk],W_f,W_g,W_o, W_i[j][2kk+1],W_f,W_g,W_o}
__global__ __launch_bounds__(256) void pack_whh(const float* __restrict__ Whf,
                                                const float* __restrict__ Whb,
                                                ushort8v* __restrict__ WT) {
  int gid = blockIdx.x * 256 + threadIdx.x;      // 2*128*256 = 65536
  int d = gid >> 15;
  int rem = gid & 32767;
  int kk = rem >> 8, j = rem & 255;
  const float* W = d ? Whb : Whf;
  int k0 = kk * 2;
  ushort8v o;
  o[0] = f2b(W[(size_t)j * 256 + k0]);
  o[1] = f2b(W[(size_t)(j + 256) * 256 + k0]);
  o[2] = f2b(W[(size_t)(j + 512) * 256 + k0]);
  o[3] = f2b(W[(size_t)(j + 768) * 256 + k0]);
  o[4] = f2b(W[(size_t)j * 256 + k0 + 1]);
  o[5] = f2b(W[(size_t)(j + 256) * 256 + k0 + 1]);
  o[6] = f2b(W[(size_t)(j + 512) * 256 + k0 + 1]);
  o[7] = f2b(W[(size_t)(j + 768) * 256 + k0 + 1]);
  WT[gid] = o;
}

// ---------------------------------------------------------------- gemm_x
// C[i][n] = emb[sent[i]] @ W_all[n]^T + bias[n];  i=(b,t), n=(d,gate,j). fp32.
__global__ __launch_bounds__(256) void gemm_x(const int* __restrict__ sent,
                                              const float* __restrict__ emb,
                                              const float* __restrict__ Wf,
                                              const float* __restrict__ Wb,
                                              const float* __restrict__ bihf,
                                              const float* __restrict__ bhhf,
                                              const float* __restrict__ bihb,
                                              const float* __restrict__ bhhb,
                                              u16* __restrict__ X4) {
  __shared__ float As[16][128];
  __shared__ float Bs[16][64];
  __shared__ int tok[128];
  int tid = threadIdx.x;
  int in = blockIdx.x;   // 0..31
  int im = blockIdx.y;   // 0..127
  if (tid < 128) tok[tid] = sent[im * 128 + tid];
  __syncthreads();
  float acc[8][4];
#pragma unroll
  for (int m = 0; m < 8; ++m)
#pragma unroll
    for (int n = 0; n < 4; ++n) acc[m][n] = 0.f;
  int ty = tid >> 4, tx = tid & 15;
  for (int kt = 0; kt < 16; ++kt) {
    int k0 = kt * 16;
#pragma unroll
    for (int l = 0; l < 2; ++l) {
      int idx = l * 256 + tid;
      int row = idx >> 2, kq = idx & 3;
      const float* ap = emb + (size_t)tok[row] * 256 + k0 + kq * 4;
      float4 av = *(const float4*)ap;
      As[kq * 4 + 0][row] = av.x; As[kq * 4 + 1][row] = av.y;
      As[kq * 4 + 2][row] = av.z; As[kq * 4 + 3][row] = av.w;
    }
    {
      int nrow = tid >> 2, kq = tid & 3;
      int ng = in * 64 + nrow;
      const float* wrow = (ng < 1024) ? (Wf + (size_t)ng * 256) : (Wb + (size_t)(ng - 1024) * 256);
      float4 bv = *(const float4*)(wrow + k0 + kq * 4);
      Bs[kq * 4 + 0][nrow] = bv.x; Bs[kq * 4 + 1][nrow] = bv.y;
      Bs[kq * 4 + 2][nrow] = bv.z; Bs[kq * 4 + 3][nrow] = bv.w;
    }
    __syncthreads();
#pragma unroll
    for (int k = 0; k < 16; ++k) {
      float4 a0 = *(const float4*)&As[k][ty * 8];
      float4 a1 = *(const float4*)&As[k][ty * 8 + 4];
      float4 bb = *(const float4*)&Bs[k][tx * 4];
      float am[8] = {a0.x, a0.y, a0.z, a0.w, a1.x, a1.y, a1.z, a1.w};
      float bn[4] = {bb.x, bb.y, bb.z, bb.w};
#pragma unroll
      for (int m = 0; m < 8; ++m)
#pragma unroll
        for (int n = 0; n < 4; ++n) acc[m][n] += am[m] * bn[n];
    }
    __syncthreads();
  }
#pragma unroll
  for (int n = 0; n < 4; ++n) {
    int ng = in * 64 + tx * 4 + n;
    int d = ng >> 10, r = ng & 1023;
    int g = r >> 8, j = r & 255;
    float bias = d ? (bihb[r] + bhhb[r]) : (bihf[r] + bhhf[r]);
#pragma unroll
    for (int m = 0; m < 8; ++m) {
      int i = im * 128 + ty * 8 + m;
      int bb_ = i >> 8, tt = i & 255;
      size_t o = ((((size_t)d * NT + tt) * NB + bb_) * 256 + j) * 4 + g;
      X4[o] = f2b(acc[m][n] + bias);
    }
  }
}

// ---------------------------------------------------------------- lstm_scan
// One block per (dir d, batch b), 1024 threads = (jj 0..255, group g 0..3).
// Group g accumulates kk = 4u+g (u=0..31): interleaved so the block's 16
// waves sweep ONE coherent sliding window over the 512 KB weight array
// (round-2-proven L2-resident shape). Partials via LDS; g0 owns c/gates.
#define ACC8(wv, h0v, h1v)                                        \
  do {                                                            \
    ai += bfl(wv.x) * h0v; af += bfh(wv.x) * h0v;                 \
    ag += bfl(wv.y) * h0v; ao += bfh(wv.y) * h0v;                 \
    ai += bfl(wv.z) * h1v; af += bfh(wv.z) * h1v;                 \
    ag += bfl(wv.w) * h1v; ao += bfh(wv.w) * h1v;                 \
  } while (0)

__global__ __launch_bounds__(1024, 4) void lstm_scan(const uint4* __restrict__ WT,
                                                     const ushort4* __restrict__ X4,
                                                     const float* __restrict__ h0,
                                                     const float* __restrict__ c0,
                                                     void* __restrict__ H, int h32) {
  int d = blockIdx.x >> 6, b = blockIdx.x & 63;
  int tid = threadIdx.x;
  int jj = tid & 255, g = tid >> 8;          // g in 0..3
  __shared__ float h_lds[256];
  __shared__ float4 plds[3][256];
  const uint4* Ws = WT + (size_t)d * 32768;  // [kk][jj], 128 x 256 entries
  float c = 0.f;
  if (g == 0) c = c0[((size_t)d * NB + b) * 256 + jj];
  if (tid < 256) h_lds[tid] = h0[((size_t)d * NB + b) * 256 + tid];
  __syncthreads();
  for (int s = 0; s < NT; ++s) {
    int t = d ? (NT - 1 - s) : s;
    float ai, af, ag, ao;
    if (g == 0) {
      ushort4 xg = X4[(((size_t)d * NT + t) * NB + b) * 256 + jj];
      ai = b2f(xg.x); af = b2f(xg.y); ag = b2f(xg.z); ao = b2f(xg.w);
    } else {
      ai = af = ag = ao = 0.f;
    }
#pragma unroll 8
    for (int u = 0; u < 32; ++u) {
      int kk = (u << 2) | g;                 // interleaved k-split
      uint4 wv = Ws[(size_t)kk * 256 + jj];
      float2 hp = *(const float2*)&h_lds[kk * 2];   // wave-uniform -> broadcast
      ACC8(wv, hp.x, hp.y);
    }
    if (g) plds[g - 1][jj] = make_float4(ai, af, ag, ao);
    __syncthreads();    // partials visible; all h_lds reads for this step done
    if (g == 0) {
      float4 p0 = plds[0][jj], p1 = plds[1][jj], p2 = plds[2][jj];
      ai += p0.x + p1.x + p2.x;
      af += p0.y + p1.y + p2.y;
      ag += p0.z + p1.z + p2.z;
      ao += p0.w + p1.w + p2.w;
      float ii = fsig(ai), ff = fsig(af), gg = ftanh(ag), oo = fsig(ao);
      c = ff * c + ii * gg;
      float h = oo * ftanh(c);
      h_lds[jj] = h;
      size_t ho = (((size_t)d * NB + b) * NT + t) * 256 + jj;
      if (h32) ((float*)H)[ho] = h; else ((u16*)H)[ho] = f2b(h);
    }
    __syncthreads();    // h_lds updated before next step reads
  }
}

// ---------------------------------------------------------------- feats
// feats[b][t][k] = sum_j hf*Wp[k][j] + hb*Wp[k][256+j] + bp[k]
__global__ __launch_bounds__(384) void feats_kernel(const void* __restrict__ H, int h32,
                                                    const float* __restrict__ Wp,
                                                    const float* __restrict__ bp,
                                                    float* __restrict__ FT) {
  __shared__ float hbuf[32][516];
  int tid = threadIdx.x;
  int i0 = blockIdx.x * 32;
  for (int idx = tid; idx < 32 * 512; idx += 384) {
    int row = idx >> 9, col = idx & 511;
    int i = i0 + row;
    int b = i >> 8, t = i & 255;
    int dd = col >> 8, jj = col & 255;
    size_t ho = (((size_t)dd * NB + b) * NT + t) * 256 + jj;
    hbuf[row][col] = h32 ? ((const float*)H)[ho] : b2f(((const u16*)H)[ho]);
  }
  __syncthreads();
  int row = tid / 12, k = tid - row * 12;  // 384 = 32*12
  const float* wp = Wp + (size_t)k * 512;
  float s = 0.f;
  for (int ccol = 0; ccol < 512; ++ccol) s += hbuf[row][ccol] * wp[ccol];
  int i = i0 + row;
  FT[(size_t)i * NKTAG + k] = s + bp[k];
}

// ---------------------------------------------------------------- viterbi
__global__ __launch_bounds__(64) void viterbi_kernel(const float* __restrict__ FT,
                                                     const float* __restrict__ trans,
                                                     const int* __restrict__ sent,
                                                     float* __restrict__ out) {
  int b = blockIdx.x, tid = threadIdx.x;
  __shared__ float trans_s[12][12];
  __shared__ float s_s[12];
  __shared__ unsigned char bp_s[256][12];
  __shared__ int path_s[256];
  for (int idx = tid; idx < 144; idx += 64) trans_s[idx / 12][idx % 12] = trans[idx];
  int cnt = 0;
#pragma unroll
  for (int q = 0; q < 4; ++q) cnt += (sent[b * NT + q * 64 + tid] > 0) ? 1 : 0;
  for (int off = 32; off; off >>= 1) cnt += __shfl_down(cnt, off);
  int len = __shfl(cnt, 0);
  if (tid < 12) s_s[tid] = (tid == START_TAG) ? 0.f : -10000.f;
  __syncthreads();
  for (int t = 0; t < NT; ++t) {
    float best = 0.f, f = 0.f;
    int barg = 0;
    if (tid < 12) {
      f = FT[((size_t)b * NT + t) * NKTAG + tid];
      best = s_s[0] + trans_s[tid][0];
      barg = 0;
#pragma unroll
      for (int fr = 1; fr < 12; ++fr) {
        float v = s_s[fr] + trans_s[tid][fr];
        if (v > best) { best = v; barg = fr; }  // strict > keeps first (jnp.argmax)
      }
    }
    __syncthreads();
    if (tid < 12) {
      s_s[tid] = best + f;
      bp_s[t][tid] = (unsigned char)barg;
    }
    __syncthreads();
  }
  if (tid == 0) {
    float bs = s_s[0];
    int bt = 0;
    for (int k = 1; k < 12; ++k)
      if (s_s[k] > bs) { bs = s_s[k]; bt = k; }
    out[NB * NT + b] = bs;  // best_score
    int x = bt;
    for (int tt = NT - 1; tt >= 0; --tt) {
      path_s[tt] = x;                  // emit BEFORE stepping back (ref semantics)
      int nxt = bp_s[tt][x];
      if (tt < len) x = nxt;
    }
  }
  __syncthreads();
#pragma unroll
  for (int q = 0; q < 4; ++q) {
    int t = q * 64 + tid;
    out[b * NT + t] = (t < len) ? (float)path_s[t] : -1.0f;
  }
}

// ---------------------------------------------------------------- launch
extern "C" void kernel_launch(void* const* d_in, const int* in_sizes, int n_in,
                              void* d_out, int out_size, void* d_ws, size_t ws_size,
                              hipStream_t stream) {
  (void)in_sizes; (void)n_in; (void)out_size;
  const int*   sent  = (const int*)d_in[0];
  const float* emb   = (const float*)d_in[2];
  const float* Wih_f = (const float*)d_in[3];
  const float* Whh_f = (const float*)d_in[4];
  const float* bih_f = (const float*)d_in[5];
  const float* bhh_f = (const float*)d_in[6];
  const float* Wih_b = (const float*)d_in[7];
  const float* Whh_b = (const float*)d_in[8];
  const float* bih_b = (const float*)d_in[9];
  const float* bhh_b = (const float*)d_in[10];
  const float* Wp    = (const float*)d_in[11];
  const float* bp    = (const float*)d_in[12];
  const float* trans = (const float*)d_in[13];
  const float* h0    = (const float*)d_in[14];
  const float* c0    = (const float*)d_in[15];
  float* out = (float*)d_out;

  char* w = (char*)d_ws;
  u16*   X4  = (u16*)w;                                   // 67108864 B
  ushort8v* WTB = (ushort8v*)(w + 67108864);              //  1048576 B
  float* FT  = (float*)(w + 67108864 + 1048576);          //   786432 B
  void*  H   = (void*)(w + 67108864 + 1048576 + 786432);  // fp32 33554432 or bf16 16777216
  const size_t base = 67108864 + 1048576 + 786432;
  int h32 = (ws_size >= base + (size_t)33554432) ? 1 : 0;

  pack_whh<<<dim3(256), dim3(256), 0, stream>>>(Whh_f, Whh_b, WTB);
  gemm_x<<<dim3(32, 128), dim3(256), 0, stream>>>(sent, emb, Wih_f, Wih_b,
                                                  bih_f, bhh_f, bih_b, bhh_b, X4);
  lstm_scan<<<dim3(128), dim3(1024), 0, stream>>>((const uint4*)WTB, (const ushort4*)X4,
                                                  h0, c0, H, h32);
  feats_kernel<<<dim3(512), dim3(384), 0, stream>>>(H, h32, Wp, bp, FT);
  viterbi_kernel<<<dim3(64), dim3(64), 0, stream>>>(FT, trans, sent, out);
}

// Round 5
// 1246.867 us; speedup vs baseline: 7.1477x; 1.3145x over previous
//
#include <hip/hip_runtime.h>

// BiLSTM-CRF on MI355X — round 5: lstm_scan with v_dot2_f32_f16 (f16 weight
// pairs, 4 VALU/kk instead of 16) + 128 KB LDS-resident weight slab
// (stream 384 KB/step instead of 512). Load shape = round-4-proven single
// coherent interleaved sliding window (kk = 32+4u+g), simple unroll-8.
//
// ws layout: X4 (67108864 B) | WTH (1048576 B) | FT (786432 B) | H (fp32 33554432
// or bf16 16777216, chosen by ws_size).
// Output (float32): d_out[0:16384] = paths (floats, -1 past length), [16384:16448] = best_score.

#define NB 64
#define NT 256
#define NKTAG 12
#define START_TAG 10
#define KK_RES 32   // kk-pairs resident in LDS -> 128 KiB

typedef unsigned short u16;
typedef _Float16 half2v __attribute__((ext_vector_type(2)));

__device__ __forceinline__ float b2f(u16 u) {
  union { unsigned int i; float f; } v; v.i = ((unsigned int)u) << 16; return v.f;
}
__device__ __forceinline__ u16 f2b(float f) {
  union { float f; unsigned int i; } v; v.f = f;
  unsigned int r = v.i + 0x7FFFu + ((v.i >> 16) & 1u);
  return (u16)(r >> 16);
}
__device__ __forceinline__ u16 f2h(float f) {
  union { _Float16 h; u16 u; } v; v.h = (_Float16)f; return v.u;
}
__device__ __forceinline__ float fsig(float x) { return 1.0f / (1.0f + __expf(-x)); }
__device__ __forceinline__ float ftanh(float x) { return 2.0f / (1.0f + __expf(-2.0f * x)) - 1.0f; }

// D = a.lo*b.lo + a.hi*b.hi + c  (v_dot2_f32_f16)
__device__ __forceinline__ float dot2h(unsigned int a, unsigned int b, float c) {
#if __has_builtin(__builtin_amdgcn_fdot2)
  union { unsigned int u; half2v h; } va, vb;
  va.u = a; vb.u = b;
  return __builtin_amdgcn_fdot2(va.h, vb.h, c, false);
#else
  float d;
  asm("v_dot2_f32_f16 %0, %1, %2, %3" : "=v"(d) : "v"(a), "v"(b), "v"(c));
  return d;
#endif
}

// ---------------------------------------------------------------- pack_whh
// WTH[d][kk][j] = uint4 { i:{k0,k1}, f:{k0,k1}, g:{k0,k1}, o:{k0,k1} } as f16
// pairs (k0 = 2kk in low half). Gate rows in Whh: i=j, f=j+256, g=j+512, o=j+768.
__global__ __launch_bounds__(256) void pack_whh(const float* __restrict__ Whf,
                                                const float* __restrict__ Whb,
                                                uint4* __restrict__ WT) {
  int gid = blockIdx.x * 256 + threadIdx.x;      // 2*128*256 = 65536
  int d = gid >> 15;
  int rem = gid & 32767;
  int kk = rem >> 8, j = rem & 255;
  const float* W = d ? Whb : Whf;
  int k0 = kk * 2;
  uint4 o;
  o.x = (unsigned int)f2h(W[(size_t)j * 256 + k0])         | ((unsigned int)f2h(W[(size_t)j * 256 + k0 + 1]) << 16);
  o.y = (unsigned int)f2h(W[(size_t)(j + 256) * 256 + k0]) | ((unsigned int)f2h(W[(size_t)(j + 256) * 256 + k0 + 1]) << 16);
  o.z = (unsigned int)f2h(W[(size_t)(j + 512) * 256 + k0]) | ((unsigned int)f2h(W[(size_t)(j + 512) * 256 + k0 + 1]) << 16);
  o.w = (unsigned int)f2h(W[(size_t)(j + 768) * 256 + k0]) | ((unsigned int)f2h(W[(size_t)(j + 768) * 256 + k0 + 1]) << 16);
  WT[gid] = o;
}

// ---------------------------------------------------------------- gemm_x
// C[i][n] = emb[sent[i]] @ W_all[n]^T + bias[n];  i=(b,t), n=(d,gate,j). fp32.
__global__ __launch_bounds__(256) void gemm_x(const int* __restrict__ sent,
                                              const float* __restrict__ emb,
                                              const float* __restrict__ Wf,
                                              const float* __restrict__ Wb,
                                              const float* __restrict__ bihf,
                                              const float* __restrict__ bhhf,
                                              const float* __restrict__ bihb,
                                              const float* __restrict__ bhhb,
                                              u16* __restrict__ X4) {
  __shared__ float As[16][128];
  __shared__ float Bs[16][64];
  __shared__ int tok[128];
  int tid = threadIdx.x;
  int in = blockIdx.x;   // 0..31
  int im = blockIdx.y;   // 0..127
  if (tid < 128) tok[tid] = sent[im * 128 + tid];
  __syncthreads();
  float acc[8][4];
#pragma unroll
  for (int m = 0; m < 8; ++m)
#pragma unroll
    for (int n = 0; n < 4; ++n) acc[m][n] = 0.f;
  int ty = tid >> 4, tx = tid & 15;
  for (int kt = 0; kt < 16; ++kt) {
    int k0 = kt * 16;
#pragma unroll
    for (int l = 0; l < 2; ++l) {
      int idx = l * 256 + tid;
      int row = idx >> 2, kq = idx & 3;
      const float* ap = emb + (size_t)tok[row] * 256 + k0 + kq * 4;
      float4 av = *(const float4*)ap;
      As[kq * 4 + 0][row] = av.x; As[kq * 4 + 1][row] = av.y;
      As[kq * 4 + 2][row] = av.z; As[kq * 4 + 3][row] = av.w;
    }
    {
      int nrow = tid >> 2, kq = tid & 3;
      int ng = in * 64 + nrow;
      const float* wrow = (ng < 1024) ? (Wf + (size_t)ng * 256) : (Wb + (size_t)(ng - 1024) * 256);
      float4 bv = *(const float4*)(wrow + k0 + kq * 4);
      Bs[kq * 4 + 0][nrow] = bv.x; Bs[kq * 4 + 1][nrow] = bv.y;
      Bs[kq * 4 + 2][nrow] = bv.z; Bs[kq * 4 + 3][nrow] = bv.w;
    }
    __syncthreads();
#pragma unroll
    for (int k = 0; k < 16; ++k) {
      float4 a0 = *(const float4*)&As[k][ty * 8];
      float4 a1 = *(const float4*)&As[k][ty * 8 + 4];
      float4 bb = *(const float4*)&Bs[k][tx * 4];
      float am[8] = {a0.x, a0.y, a0.z, a0.w, a1.x, a1.y, a1.z, a1.w};
      float bn[4] = {bb.x, bb.y, bb.z, bb.w};
#pragma unroll
      for (int m = 0; m < 8; ++m)
#pragma unroll
        for (int n = 0; n < 4; ++n) acc[m][n] += am[m] * bn[n];
    }
    __syncthreads();
  }
#pragma unroll
  for (int n = 0; n < 4; ++n) {
    int ng = in * 64 + tx * 4 + n;
    int d = ng >> 10, r = ng & 1023;
    int g = r >> 8, j = r & 255;
    float bias = d ? (bihb[r] + bhhb[r]) : (bihf[r] + bhhf[r]);
#pragma unroll
    for (int m = 0; m < 8; ++m) {
      int i = im * 128 + ty * 8 + m;
      int bb_ = i >> 8, tt = i & 255;
      size_t o = ((((size_t)d * NT + tt) * NB + bb_) * 256 + j) * 4 + g;
      X4[o] = f2b(acc[m][n] + bias);
    }
  }
}

// ---------------------------------------------------------------- lstm_scan
// One block per (dir d, batch b), 1024 threads = (jj 0..255, group g 0..3).
// Group g: resident kk = g*8+r (r 0..7) from LDS slab; streamed kk = 32+4u+g
// (u 0..23) — one coherent sliding window over 384 KB (round-4 shape).
// h kept as packed f16 pairs in LDS (dword h2s[kk] = {h[2kk], h[2kk+1]}).
// Per kk: 4 x v_dot2_f32_f16. Partials via LDS; g0 owns c/gates.
__global__ __launch_bounds__(1024, 4) void lstm_scan(const uint4* __restrict__ WT,
                                                     const ushort4* __restrict__ X4,
                                                     const float* __restrict__ h0,
                                                     const float* __restrict__ c0,
                                                     void* __restrict__ H, int h32) {
  int d = blockIdx.x >> 6, b = blockIdx.x & 63;
  int tid = threadIdx.x;
  int jj = tid & 255, g = tid >> 8;          // g in 0..3
  __shared__ uint4 wlds[KK_RES * 256];       // 131072 B resident weight slab
  __shared__ unsigned int h2s[128];          // packed f16 h pairs
  __shared__ float4 plds[3][256];            // 12288 B partials
  const uint4* Ws = WT + (size_t)d * 32768;  // [kk][jj], 128 x 256 entries
  for (int e = tid; e < KK_RES * 256; e += 1024) wlds[e] = Ws[e];
  float c = 0.f;
  if (g == 0) c = c0[((size_t)d * NB + b) * 256 + jj];
  if (tid < 256) ((u16*)h2s)[tid] = f2h(h0[((size_t)d * NB + b) * 256 + tid]);
  __syncthreads();
  for (int s = 0; s < NT; ++s) {
    int t = d ? (NT - 1 - s) : s;
    float ai, af, ag, ao;
    if (g == 0) {
      ushort4 xg = X4[(((size_t)d * NT + t) * NB + b) * 256 + jj];
      ai = b2f(xg.x); af = b2f(xg.y); ag = b2f(xg.z); ao = b2f(xg.w);
    } else {
      ai = af = ag = ao = 0.f;
    }
    // LDS-resident region: 8 kk per group
#pragma unroll
    for (int r = 0; r < 8; ++r) {
      int kk = g * 8 + r;
      uint4 wv = wlds[(kk << 8) | jj];
      unsigned int hp = h2s[kk];           // wave-uniform -> broadcast
      ai = dot2h(wv.x, hp, ai); af = dot2h(wv.y, hp, af);
      ag = dot2h(wv.z, hp, ag); ao = dot2h(wv.w, hp, ao);
    }
    // streamed region: interleaved sweep, single coherent window
#pragma unroll 8
    for (int u = 0; u < 24; ++u) {
      int kk = KK_RES + (u << 2) + g;
      uint4 wv = Ws[(size_t)kk * 256 + jj];
      unsigned int hp = h2s[kk];
      ai = dot2h(wv.x, hp, ai); af = dot2h(wv.y, hp, af);
      ag = dot2h(wv.z, hp, ag); ao = dot2h(wv.w, hp, ao);
    }
    if (g) plds[g - 1][jj] = make_float4(ai, af, ag, ao);
    __syncthreads();    // partials visible; all h2s reads for this step done
    if (g == 0) {
      float4 p0 = plds[0][jj], p1 = plds[1][jj], p2 = plds[2][jj];
      ai += p0.x + p1.x + p2.x;
      af += p0.y + p1.y + p2.y;
      ag += p0.z + p1.z + p2.z;
      ao += p0.w + p1.w + p2.w;
      float ii = fsig(ai), ff = fsig(af), gg = ftanh(ag), oo = fsig(ao);
      c = ff * c + ii * gg;
      float h = oo * ftanh(c);
      ((u16*)h2s)[jj] = f2h(h);
      size_t ho = (((size_t)d * NB + b) * NT + t) * 256 + jj;
      if (h32) ((float*)H)[ho] = h; else ((u16*)H)[ho] = f2b(h);
    }
    __syncthreads();    // h2s updated before next step reads
  }
}

// ---------------------------------------------------------------- feats
// feats[b][t][k] = sum_j hf*Wp[k][j] + hb*Wp[k][256+j] + bp[k]
__global__ __launch_bounds__(384) void feats_kernel(const void* __restrict__ H, int h32,
                                                    const float* __restrict__ Wp,
                                                    const float* __restrict__ bp,
                                                    float* __restrict__ FT) {
  __shared__ float hbuf[32][516];
  int tid = threadIdx.x;
  int i0 = blockIdx.x * 32;
  for (int idx = tid; idx < 32 * 512; idx += 384) {
    int row = idx >> 9, col = idx & 511;
    int i = i0 + row;
    int b = i >> 8, t = i & 255;
    int dd = col >> 8, jj = col & 255;
    size_t ho = (((size_t)dd * NB + b) * NT + t) * 256 + jj;
    hbuf[row][col] = h32 ? ((const float*)H)[ho] : b2f(((const u16*)H)[ho]);
  }
  __syncthreads();
  int row = tid / 12, k = tid - row * 12;  // 384 = 32*12
  const float* wp = Wp + (size_t)k * 512;
  float s = 0.f;
  for (int ccol = 0; ccol < 512; ++ccol) s += hbuf[row][ccol] * wp[ccol];
  int i = i0 + row;
  FT[(size_t)i * NKTAG + k] = s + bp[k];
}

// ---------------------------------------------------------------- viterbi
__global__ __launch_bounds__(64) void viterbi_kernel(const float* __restrict__ FT,
                                                     const float* __restrict__ trans,
                                                     const int* __restrict__ sent,
                                                     float* __restrict__ out) {
  int b = blockIdx.x, tid = threadIdx.x;
  __shared__ float trans_s[12][12];
  __shared__ float s_s[12];
  __shared__ unsigned char bp_s[256][12];
  __shared__ int path_s[256];
  for (int idx = tid; idx < 144; idx += 64) trans_s[idx / 12][idx % 12] = trans[idx];
  int cnt = 0;
#pragma unroll
  for (int q = 0; q < 4; ++q) cnt += (sent[b * NT + q * 64 + tid] > 0) ? 1 : 0;
  for (int off = 32; off; off >>= 1) cnt += __shfl_down(cnt, off);
  int len = __shfl(cnt, 0);
  if (tid < 12) s_s[tid] = (tid == START_TAG) ? 0.f : -10000.f;
  __syncthreads();
  for (int t = 0; t < NT; ++t) {
    float best = 0.f, f = 0.f;
    int barg = 0;
    if (tid < 12) {
      f = FT[((size_t)b * NT + t) * NKTAG + tid];
      best = s_s[0] + trans_s[tid][0];
      barg = 0;
#pragma unroll
      for (int fr = 1; fr < 12; ++fr) {
        float v = s_s[fr] + trans_s[tid][fr];
        if (v > best) { best = v; barg = fr; }  // strict > keeps first (jnp.argmax)
      }
    }
    __syncthreads();
    if (tid < 12) {
      s_s[tid] = best + f;
      bp_s[t][tid] = (unsigned char)barg;
    }
    __syncthreads();
  }
  if (tid == 0) {
    float bs = s_s[0];
    int bt = 0;
    for (int k = 1; k < 12; ++k)
      if (s_s[k] > bs) { bs = s_s[k]; bt = k; }
    out[NB * NT + b] = bs;  // best_score
    int x = bt;
    for (int tt = NT - 1; tt >= 0; --tt) {
      path_s[tt] = x;                  // emit BEFORE stepping back (ref semantics)
      int nxt = bp_s[tt][x];
      if (tt < len) x = nxt;
    }
  }
  __syncthreads();
#pragma unroll
  for (int q = 0; q < 4; ++q) {
    int t = q * 64 + tid;
    out[b * NT + t] = (t < len) ? (float)path_s[t] : -1.0f;
  }
}

// ---------------------------------------------------------------- launch
extern "C" void kernel_launch(void* const* d_in, const int* in_sizes, int n_in,
                              void* d_out, int out_size, void* d_ws, size_t ws_size,
                              hipStream_t stream) {
  (void)in_sizes; (void)n_in; (void)out_size;
  const int*   sent  = (const int*)d_in[0];
  const float* emb   = (const float*)d_in[2];
  const float* Wih_f = (const float*)d_in[3];
  const float* Whh_f = (const float*)d_in[4];
  const float* bih_f = (const float*)d_in[5];
  const float* bhh_f = (const float*)d_in[6];
  const float* Wih_b = (const float*)d_in[7];
  const float* Whh_b = (const float*)d_in[8];
  const float* bih_b = (const float*)d_in[9];
  const float* bhh_b = (const float*)d_in[10];
  const float* Wp    = (const float*)d_in[11];
  const float* bp    = (const float*)d_in[12];
  const float* trans = (const float*)d_in[13];
  const float* h0    = (const float*)d_in[14];
  const float* c0    = (const float*)d_in[15];
  float* out = (float*)d_out;

  char* w = (char*)d_ws;
  u16*   X4  = (u16*)w;                                   // 67108864 B
  uint4* WTH = (uint4*)(w + 67108864);                    //  1048576 B
  float* FT  = (float*)(w + 67108864 + 1048576);          //   786432 B
  void*  H   = (void*)(w + 67108864 + 1048576 + 786432);  // fp32 33554432 or bf16 16777216
  const size_t base = 67108864 + 1048576 + 786432;
  int h32 = (ws_size >= base + (size_t)33554432) ? 1 : 0;

  pack_whh<<<dim3(256), dim3(256), 0, stream>>>(Whh_f, Whh_b, WTH);
  gemm_x<<<dim3(32, 128), dim3(256), 0, stream>>>(sent, emb, Wih_f, Wih_b,
                                                  bih_f, bhh_f, bih_b, bhh_b, X4);
  lstm_scan<<<dim3(128), dim3(1024), 0, stream>>>(WTH, (const ushort4*)X4, h0, c0, H, h32);
  feats_kernel<<<dim3(512), dim3(384), 0, stream>>>(H, h32, Wp, bp, FT);
  viterbi_kernel<<<dim3(64), dim3(64), 0, stream>>>(FT, trans, sent, out);
}

// Round 6
// 799.167 us; speedup vs baseline: 11.1519x; 1.5602x over previous
//
#include <hip/hip_runtime.h>

// BiLSTM-CRF on MI355X — round 6: weights are step-invariant, so park them.
// kk partition (of 128): 32 in LDS slab (128 KB) | 64 persistent in VGPRs
// (16 uint4/thread x 4 groups, static-indexed) | 32 streamed (kk 32..63,
// one coherent interleaved window = round-4/5-proven L2-resident shape).
// Streamed bytes/step: 384 KB -> 128 KB.
//
// ws layout: X4 (67108864 B) | WTH (1048576 B) | FT (786432 B) | H (fp32 33554432
// or bf16 16777216, chosen by ws_size).
// Output (float32): d_out[0:16384] = paths (floats, -1 past length), [16384:16448] = best_score.

#define NB 64
#define NT 256
#define NKTAG 12
#define START_TAG 10
#define KK_RES 32   // kk-pairs resident in LDS -> 128 KiB
#define KK_STR 8    // streamed kk per group (kk = 32 + 4u + g)
#define KK_REG 16   // register-resident kk per thread (kk = 64 + 4r + g)

typedef unsigned short u16;
typedef _Float16 half2v __attribute__((ext_vector_type(2)));

__device__ __forceinline__ float b2f(u16 u) {
  union { unsigned int i; float f; } v; v.i = ((unsigned int)u) << 16; return v.f;
}
__device__ __forceinline__ u16 f2b(float f) {
  union { float f; unsigned int i; } v; v.f = f;
  unsigned int r = v.i + 0x7FFFu + ((v.i >> 16) & 1u);
  return (u16)(r >> 16);
}
__device__ __forceinline__ u16 f2h(float f) {
  union { _Float16 h; u16 u; } v; v.h = (_Float16)f; return v.u;
}
__device__ __forceinline__ float fsig(float x) { return 1.0f / (1.0f + __expf(-x)); }
__device__ __forceinline__ float ftanh(float x) { return 2.0f / (1.0f + __expf(-2.0f * x)) - 1.0f; }

// D = a.lo*b.lo + a.hi*b.hi + c  (v_dot2_f32_f16)
__device__ __forceinline__ float dot2h(unsigned int a, unsigned int b, float c) {
#if __has_builtin(__builtin_amdgcn_fdot2)
  union { unsigned int u; half2v h; } va, vb;
  va.u = a; vb.u = b;
  return __builtin_amdgcn_fdot2(va.h, vb.h, c, false);
#else
  float d;
  asm("v_dot2_f32_f16 %0, %1, %2, %3" : "=v"(d) : "v"(a), "v"(b), "v"(c));
  return d;
#endif
}

// ---------------------------------------------------------------- pack_whh
// WTH[d][kk][j] = uint4 { i:{k0,k1}, f:{k0,k1}, g:{k0,k1}, o:{k0,k1} } as f16
// pairs (k0 = 2kk in low half). Gate rows in Whh: i=j, f=j+256, g=j+512, o=j+768.
__global__ __launch_bounds__(256) void pack_whh(const float* __restrict__ Whf,
                                                const float* __restrict__ Whb,
                                                uint4* __restrict__ WT) {
  int gid = blockIdx.x * 256 + threadIdx.x;      // 2*128*256 = 65536
  int d = gid >> 15;
  int rem = gid & 32767;
  int kk = rem >> 8, j = rem & 255;
  const float* W = d ? Whb : Whf;
  int k0 = kk * 2;
  uint4 o;
  o.x = (unsigned int)f2h(W[(size_t)j * 256 + k0])         | ((unsigned int)f2h(W[(size_t)j * 256 + k0 + 1]) << 16);
  o.y = (unsigned int)f2h(W[(size_t)(j + 256) * 256 + k0]) | ((unsigned int)f2h(W[(size_t)(j + 256) * 256 + k0 + 1]) << 16);
  o.z = (unsigned int)f2h(W[(size_t)(j + 512) * 256 + k0]) | ((unsigned int)f2h(W[(size_t)(j + 512) * 256 + k0 + 1]) << 16);
  o.w = (unsigned int)f2h(W[(size_t)(j + 768) * 256 + k0]) | ((unsigned int)f2h(W[(size_t)(j + 768) * 256 + k0 + 1]) << 16);
  WT[gid] = o;
}

// ---------------------------------------------------------------- gemm_x
// C[i][n] = emb[sent[i]] @ W_all[n]^T + bias[n];  i=(b,t), n=(d,gate,j). fp32.
__global__ __launch_bounds__(256) void gemm_x(const int* __restrict__ sent,
                                              const float* __restrict__ emb,
                                              const float* __restrict__ Wf,
                                              const float* __restrict__ Wb,
                                              const float* __restrict__ bihf,
                                              const float* __restrict__ bhhf,
                                              const float* __restrict__ bihb,
                                              const float* __restrict__ bhhb,
                                              u16* __restrict__ X4) {
  __shared__ float As[16][128];
  __shared__ float Bs[16][64];
  __shared__ int tok[128];
  int tid = threadIdx.x;
  int in = blockIdx.x;   // 0..31
  int im = blockIdx.y;   // 0..127
  if (tid < 128) tok[tid] = sent[im * 128 + tid];
  __syncthreads();
  float acc[8][4];
#pragma unroll
  for (int m = 0; m < 8; ++m)
#pragma unroll
    for (int n = 0; n < 4; ++n) acc[m][n] = 0.f;
  int ty = tid >> 4, tx = tid & 15;
  for (int kt = 0; kt < 16; ++kt) {
    int k0 = kt * 16;
#pragma unroll
    for (int l = 0; l < 2; ++l) {
      int idx = l * 256 + tid;
      int row = idx >> 2, kq = idx & 3;
      const float* ap = emb + (size_t)tok[row] * 256 + k0 + kq * 4;
      float4 av = *(const float4*)ap;
      As[kq * 4 + 0][row] = av.x; As[kq * 4 + 1][row] = av.y;
      As[kq * 4 + 2][row] = av.z; As[kq * 4 + 3][row] = av.w;
    }
    {
      int nrow = tid >> 2, kq = tid & 3;
      int ng = in * 64 + nrow;
      const float* wrow = (ng < 1024) ? (Wf + (size_t)ng * 256) : (Wb + (size_t)(ng - 1024) * 256);
      float4 bv = *(const float4*)(wrow + k0 + kq * 4);
      Bs[kq * 4 + 0][nrow] = bv.x; Bs[kq * 4 + 1][nrow] = bv.y;
      Bs[kq * 4 + 2][nrow] = bv.z; Bs[kq * 4 + 3][nrow] = bv.w;
    }
    __syncthreads();
#pragma unroll
    for (int k = 0; k < 16; ++k) {
      float4 a0 = *(const float4*)&As[k][ty * 8];
      float4 a1 = *(const float4*)&As[k][ty * 8 + 4];
      float4 bb = *(const float4*)&Bs[k][tx * 4];
      float am[8] = {a0.x, a0.y, a0.z, a0.w, a1.x, a1.y, a1.z, a1.w};
      float bn[4] = {bb.x, bb.y, bb.z, bb.w};
#pragma unroll
      for (int m = 0; m < 8; ++m)
#pragma unroll
        for (int n = 0; n < 4; ++n) acc[m][n] += am[m] * bn[n];
    }
    __syncthreads();
  }
#pragma unroll
  for (int n = 0; n < 4; ++n) {
    int ng = in * 64 + tx * 4 + n;
    int d = ng >> 10, r = ng & 1023;
    int g = r >> 8, j = r & 255;
    float bias = d ? (bihb[r] + bhhb[r]) : (bihf[r] + bhhf[r]);
#pragma unroll
    for (int m = 0; m < 8; ++m) {
      int i = im * 128 + ty * 8 + m;
      int bb_ = i >> 8, tt = i & 255;
      size_t o = ((((size_t)d * NT + tt) * NB + bb_) * 256 + j) * 4 + g;
      X4[o] = f2b(acc[m][n] + bias);
    }
  }
}

// ---------------------------------------------------------------- lstm_scan
// One block per (dir d, batch b), 1024 threads = (jj 0..255, group g 0..3).
// Group g per step: 8 streamed kk (32+4u+g: coherent window, issued first so
// they fly under the LDS/reg work), 8 LDS-slab kk (g*8+r), 16 register kk
// (64+4r+g, persistent uint4 wreg[16], loaded once, static-indexed).
// h packed f16 pairs in LDS. Partials via LDS; g0 owns c/gates.
__global__ __launch_bounds__(1024, 4) void lstm_scan(const uint4* __restrict__ WT,
                                                     const ushort4* __restrict__ X4,
                                                     const float* __restrict__ h0,
                                                     const float* __restrict__ c0,
                                                     void* __restrict__ H, int h32) {
  int d = blockIdx.x >> 6, b = blockIdx.x & 63;
  int tid = threadIdx.x;
  int jj = tid & 255, g = tid >> 8;          // g in 0..3
  __shared__ uint4 wlds[KK_RES * 256];       // 131072 B resident weight slab
  __shared__ unsigned int h2s[128];          // packed f16 h pairs
  __shared__ float4 plds[3][256];            // 12288 B partials
  const uint4* Ws = WT + (size_t)d * 32768;  // [kk][jj], 128 x 256 entries
  for (int e = tid; e < KK_RES * 256; e += 1024) wlds[e] = Ws[e];
  // persistent register weights: kk = 64 + 4r + g  (static unroll, rule #20)
  uint4 wreg[KK_REG];
#pragma unroll
  for (int r = 0; r < KK_REG; ++r)
    wreg[r] = Ws[(size_t)(64 + (r << 2) + g) * 256 + jj];
  float c = 0.f;
  if (g == 0) c = c0[((size_t)d * NB + b) * 256 + jj];
  if (tid < 256) ((u16*)h2s)[tid] = f2h(h0[((size_t)d * NB + b) * 256 + tid]);
  __syncthreads();
  for (int s = 0; s < NT; ++s) {
    int t = d ? (NT - 1 - s) : s;
    float ai, af, ag, ao;
    if (g == 0) {
      ushort4 xg = X4[(((size_t)d * NT + t) * NB + b) * 256 + jj];
      ai = b2f(xg.x); af = b2f(xg.y); ag = b2f(xg.z); ao = b2f(xg.w);
    } else {
      ai = af = ag = ao = 0.f;
    }
    // streamed region first: loads go in flight, consumed after issue
#pragma unroll
    for (int u = 0; u < KK_STR; ++u) {
      int kk = KK_RES + (u << 2) + g;
      uint4 wv = Ws[(size_t)kk * 256 + jj];
      unsigned int hp = h2s[kk];
      ai = dot2h(wv.x, hp, ai); af = dot2h(wv.y, hp, af);
      ag = dot2h(wv.z, hp, ag); ao = dot2h(wv.w, hp, ao);
    }
    // LDS-resident slab: 8 kk per group
#pragma unroll
    for (int r = 0; r < 8; ++r) {
      int kk = g * 8 + r;
      uint4 wv = wlds[(kk << 8) | jj];
      unsigned int hp = h2s[kk];           // wave-uniform -> broadcast
      ai = dot2h(wv.x, hp, ai); af = dot2h(wv.y, hp, af);
      ag = dot2h(wv.z, hp, ag); ao = dot2h(wv.w, hp, ao);
    }
    // register-resident region: 16 kk per thread
#pragma unroll
    for (int r = 0; r < KK_REG; ++r) {
      int kk = 64 + (r << 2) + g;
      uint4 wv = wreg[r];
      unsigned int hp = h2s[kk];
      ai = dot2h(wv.x, hp, ai); af = dot2h(wv.y, hp, af);
      ag = dot2h(wv.z, hp, ag); ao = dot2h(wv.w, hp, ao);
    }
    if (g) plds[g - 1][jj] = make_float4(ai, af, ag, ao);
    __syncthreads();    // partials visible; all h2s reads for this step done
    if (g == 0) {
      float4 p0 = plds[0][jj], p1 = plds[1][jj], p2 = plds[2][jj];
      ai += p0.x + p1.x + p2.x;
      af += p0.y + p1.y + p2.y;
      ag += p0.z + p1.z + p2.z;
      ao += p0.w + p1.w + p2.w;
      float ii = fsig(ai), ff = fsig(af), gg = ftanh(ag), oo = fsig(ao);
      c = ff * c + ii * gg;
      float h = oo * ftanh(c);
      ((u16*)h2s)[jj] = f2h(h);
      size_t ho = (((size_t)d * NB + b) * NT + t) * 256 + jj;
      if (h32) ((float*)H)[ho] = h; else ((u16*)H)[ho] = f2b(h);
    }
    __syncthreads();    // h2s updated before next step reads
  }
}

// ---------------------------------------------------------------- feats
// feats[b][t][k] = sum_j hf*Wp[k][j] + hb*Wp[k][256+j] + bp[k]
__global__ __launch_bounds__(384) void feats_kernel(const void* __restrict__ H, int h32,
                                                    const float* __restrict__ Wp,
                                                    const float* __restrict__ bp,
                                                    float* __restrict__ FT) {
  __shared__ float hbuf[32][516];
  int tid = threadIdx.x;
  int i0 = blockIdx.x * 32;
  for (int idx = tid; idx < 32 * 512; idx += 384) {
    int row = idx >> 9, col = idx & 511;
    int i = i0 + row;
    int b = i >> 8, t = i & 255;
    int dd = col >> 8, jj = col & 255;
    size_t ho = (((size_t)dd * NB + b) * NT + t) * 256 + jj;
    hbuf[row][col] = h32 ? ((const float*)H)[ho] : b2f(((const u16*)H)[ho]);
  }
  __syncthreads();
  int row = tid / 12, k = tid - row * 12;  // 384 = 32*12
  const float* wp = Wp + (size_t)k * 512;
  float s = 0.f;
  for (int ccol = 0; ccol < 512; ++ccol) s += hbuf[row][ccol] * wp[ccol];
  int i = i0 + row;
  FT[(size_t)i * NKTAG + k] = s + bp[k];
}

// ---------------------------------------------------------------- viterbi
__global__ __launch_bounds__(64) void viterbi_kernel(const float* __restrict__ FT,
                                                     const float* __restrict__ trans,
                                                     const int* __restrict__ sent,
                                                     float* __restrict__ out) {
  int b = blockIdx.x, tid = threadIdx.x;
  __shared__ float trans_s[12][12];
  __shared__ float s_s[12];
  __shared__ unsigned char bp_s[256][12];
  __shared__ int path_s[256];
  for (int idx = tid; idx < 144; idx += 64) trans_s[idx / 12][idx % 12] = trans[idx];
  int cnt = 0;
#pragma unroll
  for (int q = 0; q < 4; ++q) cnt += (sent[b * NT + q * 64 + tid] > 0) ? 1 : 0;
  for (int off = 32; off; off >>= 1) cnt += __shfl_down(cnt, off);
  int len = __shfl(cnt, 0);
  if (tid < 12) s_s[tid] = (tid == START_TAG) ? 0.f : -10000.f;
  __syncthreads();
  for (int t = 0; t < NT; ++t) {
    float best = 0.f, f = 0.f;
    int barg = 0;
    if (tid < 12) {
      f = FT[((size_t)b * NT + t) * NKTAG + tid];
      best = s_s[0] + trans_s[tid][0];
      barg = 0;
#pragma unroll
      for (int fr = 1; fr < 12; ++fr) {
        float v = s_s[fr] + trans_s[tid][fr];
        if (v > best) { best = v; barg = fr; }  // strict > keeps first (jnp.argmax)
      }
    }
    __syncthreads();
    if (tid < 12) {
      s_s[tid] = best + f;
      bp_s[t][tid] = (unsigned char)barg;
    }
    __syncthreads();
  }
  if (tid == 0) {
    float bs = s_s[0];
    int bt = 0;
    for (int k = 1; k < 12; ++k)
      if (s_s[k] > bs) { bs = s_s[k]; bt = k; }
    out[NB * NT + b] = bs;  // best_score
    int x = bt;
    for (int tt = NT - 1; tt >= 0; --tt) {
      path_s[tt] = x;                  // emit BEFORE stepping back (ref semantics)
      int nxt = bp_s[tt][x];
      if (tt < len) x = nxt;
    }
  }
  __syncthreads();
#pragma unroll
  for (int q = 0; q < 4; ++q) {
    int t = q * 64 + tid;
    out[b * NT + t] = (t < len) ? (float)path_s[t] : -1.0f;
  }
}

// ---------------------------------------------------------------- launch
extern "C" void kernel_launch(void* const* d_in, const int* in_sizes, int n_in,
                              void* d_out, int out_size, void* d_ws, size_t ws_size,
                              hipStream_t stream) {
  (void)in_sizes; (void)n_in; (void)out_size;
  const int*   sent  = (const int*)d_in[0];
  const float* emb   = (const float*)d_in[2];
  const float* Wih_f = (const float*)d_in[3];
  const float* Whh_f = (const float*)d_in[4];
  const float* bih_f = (const float*)d_in[5];
  const float* bhh_f = (const float*)d_in[6];
  const float* Wih_b = (const float*)d_in[7];
  const float* Whh_b = (const float*)d_in[8];
  const float* bih_b = (const float*)d_in[9];
  const float* bhh_b = (const float*)d_in[10];
  const float* Wp    = (const float*)d_in[11];
  const float* bp    = (const float*)d_in[12];
  const float* trans = (const float*)d_in[13];
  const float* h0    = (const float*)d_in[14];
  const float* c0    = (const float*)d_in[15];
  float* out = (float*)d_out;

  char* w = (char*)d_ws;
  u16*   X4  = (u16*)w;                                   // 67108864 B
  uint4* WTH = (uint4*)(w + 67108864);                    //  1048576 B
  float* FT  = (float*)(w + 67108864 + 1048576);          //   786432 B
  void*  H   = (void*)(w + 67108864 + 1048576 + 786432);  // fp32 33554432 or bf16 16777216
  const size_t base = 67108864 + 1048576 + 786432;
  int h32 = (ws_size >= base + (size_t)33554432) ? 1 : 0;

  pack_whh<<<dim3(256), dim3(256), 0, stream>>>(Whh_f, Whh_b, WTH);
  gemm_x<<<dim3(32, 128), dim3(256), 0, stream>>>(sent, emb, Wih_f, Wih_b,
                                                  bih_f, bhh_f, bih_b, bhh_b, X4);
  lstm_scan<<<dim3(128), dim3(1024), 0, stream>>>(WTH, (const ushort4*)X4, h0, c0, H, h32);
  feats_kernel<<<dim3(512), dim3(384), 0, stream>>>(H, h32, Wp, bp, FT);
  viterbi_kernel<<<dim3(64), dim3(64), 0, stream>>>(FT, trans, sent, out);
}